// Round 2
// baseline (543.341 us; speedup 1.0000x reference)
//
#include <hip/hip_runtime.h>

typedef _Float16 half8  __attribute__((ext_vector_type(8)));
typedef _Float16 half4v __attribute__((ext_vector_type(4)));
typedef _Float16 half2v __attribute__((ext_vector_type(2)));
typedef float    f32x4  __attribute__((ext_vector_type(4)));

#define ITER 8

__device__ __forceinline__ int swz(int row) {
    return ((row ^ (row >> 3)) & 15) << 4;   // XOR bits 4-7: 16B-granule swizzle, b128-safe
}

// One workgroup = ITER consecutive (b,h,n) 128x128 attention blocks, software-pipelined:
// K/V of block i+1 are prefetched to registers while block i computes.
// 8 waves, wave w owns q-rows [16w,16w+16).
// LDS: [0,32K) K fp16 [128][128] swizzled (later overlaid by P: 8 waves x [16][128] fp16)
//      [32K,64K) Vt fp16 [128][128] = V^T, swizzled.
__global__ __launch_bounds__(512, 4) void battn_kernel(
    const float* __restrict__ Q, const float* __restrict__ K,
    const float* __restrict__ V, float* __restrict__ O)
{
    extern __shared__ __align__(16) char smem[];
    const int tid  = threadIdx.x;
    const int lane = tid & 63;
    const int w    = tid >> 6;
    const int la   = lane & 15;
    const int u    = lane >> 4;

    float4 kreg[8];
    float4 vreg[2][4];

    auto loadKV = [&](const float* Kb, const float* Vb) {
#pragma unroll
        for (int it2 = 0; it2 < 8; ++it2)
            kreg[it2] = *(const float4*)(Kb + it2 * 2048 + tid * 4);
#pragma unroll
        for (int it2 = 0; it2 < 2; ++it2) {
            const int tau = it2 * 512 + tid;
            const int d0 = (tau & 15) * 8;
            const int j0 = (tau >> 4) * 2;
            vreg[it2][0] = *(const float4*)(Vb + j0 * 128 + d0);
            vreg[it2][1] = *(const float4*)(Vb + j0 * 128 + d0 + 4);
            vreg[it2][2] = *(const float4*)(Vb + (j0 + 1) * 128 + d0);
            vreg[it2][3] = *(const float4*)(Vb + (j0 + 1) * 128 + d0 + 4);
        }
    };

    const size_t base0 = (size_t)blockIdx.x * ITER * (128 * 128);
    loadKV(K + base0, V + base0);                      // prologue prefetch (block 0)

    for (int it = 0; it < ITER; ++it) {
        const size_t base = base0 + (size_t)it * (128 * 128);
        const float* Qb = Q + base;
        float*       Ob = O + base;

        // ---- issue Q loads (current block) early; latency hides under staging ----
        float4 qld[8];
        {
            const float* qrow = Qb + (w * 16 + la) * 128;
#pragma unroll
            for (int kk = 0; kk < 4; ++kk) {
                qld[2 * kk]     = *(const float4*)(qrow + kk * 32 + u * 8);
                qld[2 * kk + 1] = *(const float4*)(qrow + kk * 32 + u * 8 + 4);
            }
        }

        __syncthreads();   // previous iteration's LDS readers are done

        // ---- stage K (regs -> LDS fp16 row-major swizzled) ----
#pragma unroll
        for (int it2 = 0; it2 < 8; ++it2) {
            const int idx = it2 * 2048 + tid * 4;
            const int row = idx >> 7;
            const int col = idx & 127;
            half4v h;
            h[0] = (_Float16)kreg[it2].x; h[1] = (_Float16)kreg[it2].y;
            h[2] = (_Float16)kreg[it2].z; h[3] = (_Float16)kreg[it2].w;
            int byte = row * 256 + col * 2;
            byte ^= swz(row);
            *(half4v*)(smem + byte) = h;
        }
        // ---- stage V transposed (Vt[d][j]) swizzled ----
#pragma unroll
        for (int it2 = 0; it2 < 2; ++it2) {
            const int tau = it2 * 512 + tid;
            const int d0 = (tau & 15) * 8;
            const int j0 = (tau >> 4) * 2;
            const float r0[8] = {vreg[it2][0].x, vreg[it2][0].y, vreg[it2][0].z, vreg[it2][0].w,
                                 vreg[it2][1].x, vreg[it2][1].y, vreg[it2][1].z, vreg[it2][1].w};
            const float r1[8] = {vreg[it2][2].x, vreg[it2][2].y, vreg[it2][2].z, vreg[it2][2].w,
                                 vreg[it2][3].x, vreg[it2][3].y, vreg[it2][3].z, vreg[it2][3].w};
#pragma unroll
            for (int i = 0; i < 8; ++i) {
                half2v h;
                h[0] = (_Float16)r0[i];
                h[1] = (_Float16)r1[i];
                const int row = d0 + i;
                int byte = 32768 + row * 256 + j0 * 2;
                byte ^= swz(row);
                *(half2v*)(smem + byte) = h;
            }
        }
        __syncthreads();

        // ---- prefetch next block's K,V (in flight during all compute below) ----
        if (it + 1 < ITER) {
            const size_t nbase = base + (128 * 128);
            loadKV(K + nbase, V + nbase);
        }

        // ---- Q fragments fp32->fp16 ----
        half8 qfrag[4];
#pragma unroll
        for (int kk = 0; kk < 4; ++kk) {
            const float4 a = qld[2 * kk];
            const float4 b = qld[2 * kk + 1];
            qfrag[kk][0] = (_Float16)a.x; qfrag[kk][1] = (_Float16)a.y;
            qfrag[kk][2] = (_Float16)a.z; qfrag[kk][3] = (_Float16)a.w;
            qfrag[kk][4] = (_Float16)b.x; qfrag[kk][5] = (_Float16)b.y;
            qfrag[kk][6] = (_Float16)b.z; qfrag[kk][7] = (_Float16)b.w;
        }

        // ---- S = Q K^T : A=Q(frag), B=K rows ----
        f32x4 acc[8];
#pragma unroll
        for (int t = 0; t < 8; ++t) acc[t] = (f32x4){0.f, 0.f, 0.f, 0.f};
#pragma unroll
        for (int t = 0; t < 8; ++t) {
#pragma unroll
            for (int kk = 0; kk < 4; ++kk) {
                const int row = t * 16 + la;
                int byte = row * 256 + kk * 64 + u * 16;
                byte ^= swz(row);
                const half8 kf = *(const half8*)(smem + byte);
                acc[t] = __builtin_amdgcn_mfma_f32_16x16x32_f16(qfrag[kk], kf, acc[t], 0, 0, 0);
            }
        }
        // acc[t][r] = S[q-sub-row = 4u+r][col = 16t+la]

        // ---- row softmax (reduce over 16 lanes sharing u) ----
        float inv[4];
#pragma unroll
        for (int r = 0; r < 4; ++r) {
            float m = acc[0][r];
#pragma unroll
            for (int t = 1; t < 8; ++t) m = fmaxf(m, acc[t][r]);
            m = fmaxf(m, __shfl_xor(m, 1));
            m = fmaxf(m, __shfl_xor(m, 2));
            m = fmaxf(m, __shfl_xor(m, 4));
            m = fmaxf(m, __shfl_xor(m, 8));
            float s = 0.f;
#pragma unroll
            for (int t = 0; t < 8; ++t) {
                const float e = __expf(acc[t][r] - m);
                acc[t][r] = e;
                s += e;
            }
            s += __shfl_xor(s, 1);
            s += __shfl_xor(s, 2);
            s += __shfl_xor(s, 4);
            s += __shfl_xor(s, 8);
            inv[r] = 1.0f / s;
        }

        __syncthreads();   // all waves done reading K before P overlays the K region

        // ---- P -> LDS fp16 (row-major per wave, swizzled) ----
#pragma unroll
        for (int t = 0; t < 8; ++t) {
#pragma unroll
            for (int r = 0; r < 4; ++r) {
                const int row = u * 4 + r;
                const int col = t * 16 + la;
                int byte = w * 4096 + row * 256 + col * 2;
                byte ^= swz(row);
                *(_Float16*)(smem + byte) = (_Float16)(acc[t][r] * inv[r]);
            }
        }
        __syncthreads();

        // ---- O^T = Vt * P^T : A=Vt rows (m=d), B=P rows (n=q) ----
        half8 pb[4];
#pragma unroll
        for (int kk = 0; kk < 4; ++kk) {
            int byte = w * 4096 + la * 256 + kk * 64 + u * 16;
            byte ^= swz(la);
            pb[kk] = *(const half8*)(smem + byte);
        }
        f32x4 oacc[8];
#pragma unroll
        for (int tt = 0; tt < 8; ++tt) oacc[tt] = (f32x4){0.f, 0.f, 0.f, 0.f};
#pragma unroll
        for (int tt = 0; tt < 8; ++tt) {
#pragma unroll
            for (int kk = 0; kk < 4; ++kk) {
                const int row = tt * 16 + la;
                int byte = 32768 + row * 256 + kk * 64 + u * 16;
                byte ^= swz(row);
                const half8 vf = *(const half8*)(smem + byte);
                oacc[tt] = __builtin_amdgcn_mfma_f32_16x16x32_f16(vf, pb[kk], oacc[tt], 0, 0, 0);
            }
        }
        // oacc[tt][r] = O[q = w*16+la][d = tt*16 + 4u + r]
#pragma unroll
        for (int tt = 0; tt < 8; ++tt) {
            const float4 ov = make_float4(oacc[tt][0], oacc[tt][1], oacc[tt][2], oacc[tt][3]);
            *(float4*)(Ob + (w * 16 + la) * 128 + tt * 16 + u * 4) = ov;
        }
    }
}

extern "C" void kernel_launch(void* const* d_in, const int* in_sizes, int n_in,
                              void* d_out, int out_size, void* d_ws, size_t ws_size,
                              hipStream_t stream) {
    const float* q = (const float*)d_in[0];
    const float* k = (const float*)d_in[1];
    const float* v = (const float*)d_in[2];
    float* o = (float*)d_out;
    const int nblocks = in_sizes[0] / (128 * 128);   // 4096
    const int nwg = nblocks / ITER;                  // 512 -> 2 WGs/CU
    battn_kernel<<<dim3(nwg), dim3(512), 65536, stream>>>(q, k, v, o);
}

// Round 3
// 266.900 us; speedup vs baseline: 2.0357x; 2.0357x over previous
//
#include <hip/hip_runtime.h>

typedef _Float16 half8  __attribute__((ext_vector_type(8)));
typedef _Float16 half4v __attribute__((ext_vector_type(4)));
typedef _Float16 half2v __attribute__((ext_vector_type(2)));
typedef float    f32x4  __attribute__((ext_vector_type(4)));

__device__ __forceinline__ int swz(int row) {
    return ((row ^ (row >> 3)) & 15) << 4;   // K/P region: 256B rows, 16 granules
}
__device__ __forceinline__ int vswz(int d) {
    return ((d ^ (d >> 3)) & 7) << 4;        // Vt region: 128B rows, 8 granules
}

// One WG = one (b,h,n) 128x128 attention block. 8 waves; wave w owns q-rows [16w,16w+16).
// LDS 48KB: [0,32K) K fp16 [128][128] swizzled (overlaid by P after QK^T)
//           [32K,48K) Vt-half fp16 [128 d][64 j], 128B rows, vswz; reused for j-half 0 then 1.
// V HBM service is deferred: half0 issued after S1 (hides under QK^T+softmax),
// half1 issued after S2 (hides under P-write + PV-half0). PV accumulates over both j-halves.
__global__ __launch_bounds__(512, 6) void battn_kernel(
    const float* __restrict__ Q, const float* __restrict__ K,
    const float* __restrict__ V, float* __restrict__ O)
{
    extern __shared__ __align__(16) char smem[];
    const int tid  = threadIdx.x;
    const int lane = tid & 63;
    const int w    = tid >> 6;
    const int la   = lane & 15;
    const int u    = lane >> 4;
    const size_t base = (size_t)blockIdx.x * (128 * 128);

    const float* Qb = Q + base;
    const float* Kb = K + base;
    const float* Vb = V + base;
    float*       Ob = O + base;

    // V staging geometry: thread -> (row pair j0,j0+1 within half, d-octet d0)
    const int jp = tid >> 4;        // 0..31
    const int c  = tid & 15;        // 0..15
    const int j0 = 2 * jp;          // within-half col index (0..62)
    const int d0 = 8 * c;           // 0..120

    // ---------------- phase 0: K + Q loads ----------------
    float4 kreg[8];
#pragma unroll
    for (int it = 0; it < 8; ++it)
        kreg[it] = *(const float4*)(Kb + it * 2048 + tid * 4);

    float4 qld[8];
    {
        const float* qrow = Qb + (w * 16 + la) * 128;
#pragma unroll
        for (int kk = 0; kk < 4; ++kk) {
            qld[2 * kk]     = *(const float4*)(qrow + kk * 32 + u * 8);
            qld[2 * kk + 1] = *(const float4*)(qrow + kk * 32 + u * 8 + 4);
        }
    }
    // Q fragments (qld dies here)
    half8 qfrag[4];
#pragma unroll
    for (int kk = 0; kk < 4; ++kk) {
        const float4 a = qld[2 * kk];
        const float4 b = qld[2 * kk + 1];
        qfrag[kk][0] = (_Float16)a.x; qfrag[kk][1] = (_Float16)a.y;
        qfrag[kk][2] = (_Float16)a.z; qfrag[kk][3] = (_Float16)a.w;
        qfrag[kk][4] = (_Float16)b.x; qfrag[kk][5] = (_Float16)b.y;
        qfrag[kk][6] = (_Float16)b.z; qfrag[kk][7] = (_Float16)b.w;
    }
    // stage K (kreg dies here)
#pragma unroll
    for (int it = 0; it < 8; ++it) {
        const int idx = it * 2048 + tid * 4;
        const int row = idx >> 7;
        const int col = idx & 127;
        half4v h;
        h[0] = (_Float16)kreg[it].x; h[1] = (_Float16)kreg[it].y;
        h[2] = (_Float16)kreg[it].z; h[3] = (_Float16)kreg[it].w;
        int byte = row * 256 + col * 2;
        byte ^= swz(row);
        *(half4v*)(smem + byte) = h;
    }
    __syncthreads();                                   // S1

    // ---------------- issue V half0 (rows j<64); hides under QK^T+softmax ----------------
    float4 va[4];
    va[0] = *(const float4*)(Vb + j0 * 128 + d0);
    va[1] = *(const float4*)(Vb + j0 * 128 + d0 + 4);
    va[2] = *(const float4*)(Vb + (j0 + 1) * 128 + d0);
    va[3] = *(const float4*)(Vb + (j0 + 1) * 128 + d0 + 4);

    // ---------------- S = Q K^T ----------------
    f32x4 acc[8];
#pragma unroll
    for (int t = 0; t < 8; ++t) acc[t] = (f32x4){0.f, 0.f, 0.f, 0.f};
#pragma unroll
    for (int t = 0; t < 8; ++t) {
#pragma unroll
        for (int kk = 0; kk < 4; ++kk) {
            const int row = t * 16 + la;
            int byte = row * 256 + kk * 64 + u * 16;
            byte ^= swz(row);
            const half8 kf = *(const half8*)(smem + byte);
            acc[t] = __builtin_amdgcn_mfma_f32_16x16x32_f16(qfrag[kk], kf, acc[t], 0, 0, 0);
        }
    }
    // acc[t][r] = S[q-sub-row = 4u+r][col = 16t+la]

    // ---------------- row softmax ----------------
    float inv[4];
#pragma unroll
    for (int r = 0; r < 4; ++r) {
        float m = acc[0][r];
#pragma unroll
        for (int t = 1; t < 8; ++t) m = fmaxf(m, acc[t][r]);
        m = fmaxf(m, __shfl_xor(m, 1));
        m = fmaxf(m, __shfl_xor(m, 2));
        m = fmaxf(m, __shfl_xor(m, 4));
        m = fmaxf(m, __shfl_xor(m, 8));
        float s = 0.f;
#pragma unroll
        for (int t = 0; t < 8; ++t) {
            const float e = __expf(acc[t][r] - m);
            acc[t][r] = e;
            s += e;
        }
        s += __shfl_xor(s, 1);
        s += __shfl_xor(s, 2);
        s += __shfl_xor(s, 4);
        s += __shfl_xor(s, 8);
        inv[r] = 1.0f / s;
    }

    __syncthreads();                                   // S2: K readers done; va drained

    // ---------------- issue V half1 (rows j>=64); hides under P-write + PV-half0 ----------
    float4 vb4[4];
    vb4[0] = *(const float4*)(Vb + (64 + j0) * 128 + d0);
    vb4[1] = *(const float4*)(Vb + (64 + j0) * 128 + d0 + 4);
    vb4[2] = *(const float4*)(Vb + (64 + j0 + 1) * 128 + d0);
    vb4[3] = *(const float4*)(Vb + (64 + j0 + 1) * 128 + d0 + 4);

    // ---------------- P -> LDS (overlay K region) ----------------
#pragma unroll
    for (int t = 0; t < 8; ++t) {
#pragma unroll
        for (int r = 0; r < 4; ++r) {
            const int row = u * 4 + r;
            const int col = t * 16 + la;
            int byte = w * 4096 + row * 256 + col * 2;
            byte ^= swz(row);
            *(_Float16*)(smem + byte) = (_Float16)(acc[t][r] * inv[r]);
        }
    }
    // ---------------- stage Vt-half0 (va dies) ----------------
    {
        const float r0[8] = {va[0].x, va[0].y, va[0].z, va[0].w,
                             va[1].x, va[1].y, va[1].z, va[1].w};
        const float r1[8] = {va[2].x, va[2].y, va[2].z, va[2].w,
                             va[3].x, va[3].y, va[3].z, va[3].w};
#pragma unroll
        for (int i = 0; i < 8; ++i) {
            half2v h;
            h[0] = (_Float16)r0[i];
            h[1] = (_Float16)r1[i];
            const int d = d0 + i;
            int byte = 32768 + d * 128 + j0 * 2;
            byte ^= vswz(d);
            *(half2v*)(smem + byte) = h;
        }
    }
    __syncthreads();                                   // S3

    // ---------------- pb: B-fragments of P (all 4 k-slabs) ----------------
    half8 pb[4];
#pragma unroll
    for (int kk = 0; kk < 4; ++kk) {
        int byte = w * 4096 + la * 256 + kk * 64 + u * 16;
        byte ^= swz(la);
        pb[kk] = *(const half8*)(smem + byte);
    }
    f32x4 oacc[8];
#pragma unroll
    for (int tt = 0; tt < 8; ++tt) oacc[tt] = (f32x4){0.f, 0.f, 0.f, 0.f};

    // ---------------- PV, j-half 0 (k-slabs 0,1) ----------------
#pragma unroll
    for (int tt = 0; tt < 8; ++tt) {
#pragma unroll
        for (int kkl = 0; kkl < 2; ++kkl) {
            const int d = tt * 16 + la;
            int byte = 32768 + d * 128 + kkl * 64 + u * 16;
            byte ^= vswz(d);
            const half8 vf = *(const half8*)(smem + byte);
            oacc[tt] = __builtin_amdgcn_mfma_f32_16x16x32_f16(vf, pb[kkl], oacc[tt], 0, 0, 0);
        }
    }
    __syncthreads();                                   // S4: Vt-half0 readers done; vb4 drained

    // ---------------- stage Vt-half1 (vb4 dies) ----------------
    {
        const float r0[8] = {vb4[0].x, vb4[0].y, vb4[0].z, vb4[0].w,
                             vb4[1].x, vb4[1].y, vb4[1].z, vb4[1].w};
        const float r1[8] = {vb4[2].x, vb4[2].y, vb4[2].z, vb4[2].w,
                             vb4[3].x, vb4[3].y, vb4[3].z, vb4[3].w};
#pragma unroll
        for (int i = 0; i < 8; ++i) {
            half2v h;
            h[0] = (_Float16)r0[i];
            h[1] = (_Float16)r1[i];
            const int d = d0 + i;
            int byte = 32768 + d * 128 + j0 * 2;
            byte ^= vswz(d);
            *(half2v*)(smem + byte) = h;
        }
    }
    __syncthreads();                                   // S5

    // ---------------- PV, j-half 1 (k-slabs 2,3) ----------------
#pragma unroll
    for (int tt = 0; tt < 8; ++tt) {
#pragma unroll
        for (int kkl = 0; kkl < 2; ++kkl) {
            const int d = tt * 16 + la;
            int byte = 32768 + d * 128 + kkl * 64 + u * 16;
            byte ^= vswz(d);
            const half8 vf = *(const half8*)(smem + byte);
            oacc[tt] = __builtin_amdgcn_mfma_f32_16x16x32_f16(vf, pb[2 + kkl], oacc[tt], 0, 0, 0);
        }
    }

    // ---------------- store O ----------------
#pragma unroll
    for (int tt = 0; tt < 8; ++tt) {
        const float4 ov = make_float4(oacc[tt][0], oacc[tt][1], oacc[tt][2], oacc[tt][3]);
        *(float4*)(Ob + (w * 16 + la) * 128 + tt * 16 + u * 4) = ov;
    }
}

extern "C" void kernel_launch(void* const* d_in, const int* in_sizes, int n_in,
                              void* d_out, int out_size, void* d_ws, size_t ws_size,
                              hipStream_t stream) {
    const float* q = (const float*)d_in[0];
    const float* k = (const float*)d_in[1];
    const float* v = (const float*)d_in[2];
    float* o = (float*)d_out;
    const int nblocks = in_sizes[0] / (128 * 128);   // 4096
    battn_kernel<<<dim3(nblocks), dim3(512), 49152, stream>>>(q, k, v, o);
}

// Round 4
// 222.123 us; speedup vs baseline: 2.4461x; 1.2016x over previous
//
#include <hip/hip_runtime.h>

typedef _Float16 half8  __attribute__((ext_vector_type(8)));
typedef _Float16 half4v __attribute__((ext_vector_type(4)));
typedef float    f32x4  __attribute__((ext_vector_type(4)));

__device__ __forceinline__ int swz(int row) {
    return ((row ^ (row >> 3)) & 15) << 4;   // 256B-row region, 16B granules
}

// One WG = one (b,h,n) 128x128 attention block. 8 waves; wave w owns:
//   QK^T/softmax: q-rows [16w,16w+16)
//   PV:           d-slab  [16w,16w+16)  (V read straight from global, no LDS)
// LDS 32KB: K fp16 [128][128] swizzled, overlaid by P fp16 [128 q][128 j] after QK^T.
__global__ __launch_bounds__(512, 6) void battn_kernel(
    const float* __restrict__ Q, const float* __restrict__ K,
    const float* __restrict__ V, float* __restrict__ O)
{
    extern __shared__ __align__(16) char smem[];
    const int tid  = threadIdx.x;
    const int lane = tid & 63;
    const int w    = tid >> 6;
    const int la   = lane & 15;
    const int u    = lane >> 4;
    const size_t base = (size_t)blockIdx.x * (128 * 128);

    const float* Qb = Q + base;
    const float* Kb = K + base;
    const float* Vb = V + base;
    float*       Ob = O + base;

    // ---------------- phase 0: K + Q loads, qfrag cvt, K->LDS ----------------
    float4 kreg[8];
#pragma unroll
    for (int it = 0; it < 8; ++it)
        kreg[it] = *(const float4*)(Kb + it * 2048 + tid * 4);

    half8 qfrag[4];
    {
        const float* qrow = Qb + (w * 16 + la) * 128;
#pragma unroll
        for (int kk = 0; kk < 4; ++kk) {
            const float4 a = *(const float4*)(qrow + kk * 32 + u * 8);
            const float4 b = *(const float4*)(qrow + kk * 32 + u * 8 + 4);
            qfrag[kk][0] = (_Float16)a.x; qfrag[kk][1] = (_Float16)a.y;
            qfrag[kk][2] = (_Float16)a.z; qfrag[kk][3] = (_Float16)a.w;
            qfrag[kk][4] = (_Float16)b.x; qfrag[kk][5] = (_Float16)b.y;
            qfrag[kk][6] = (_Float16)b.z; qfrag[kk][7] = (_Float16)b.w;
        }
    }
#pragma unroll
    for (int it = 0; it < 8; ++it) {
        const int idx = it * 2048 + tid * 4;
        const int row = idx >> 7;
        const int col = idx & 127;
        half4v h;
        h[0] = (_Float16)kreg[it].x; h[1] = (_Float16)kreg[it].y;
        h[2] = (_Float16)kreg[it].z; h[3] = (_Float16)kreg[it].w;
        int byte = row * 256 + col * 2;
        byte ^= swz(row);
        *(half4v*)(smem + byte) = h;
    }
    __syncthreads();                                   // S1

    // ---- issue V loads, low half (j-slabs kk=0,1): in flight during QK^T ----
    // A-frag for PV: lane (la,u) needs V[j = kk*32 + u*8 + i][d = 16w + la]
    float vlo[16];
#pragma unroll
    for (int kk = 0; kk < 2; ++kk)
#pragma unroll
        for (int i = 0; i < 8; ++i)
            vlo[kk * 8 + i] = Vb[(kk * 32 + u * 8 + i) * 128 + w * 16 + la];

    // ---------------- S = Q K^T ----------------
    f32x4 acc[8];
#pragma unroll
    for (int t = 0; t < 8; ++t) acc[t] = (f32x4){0.f, 0.f, 0.f, 0.f};
#pragma unroll
    for (int t = 0; t < 8; ++t) {
#pragma unroll
        for (int kk = 0; kk < 4; ++kk) {
            const int row = t * 16 + la;
            int byte = row * 256 + kk * 64 + u * 16;
            byte ^= swz(row);
            const half8 kf = *(const half8*)(smem + byte);
            acc[t] = __builtin_amdgcn_mfma_f32_16x16x32_f16(qfrag[kk], kf, acc[t], 0, 0, 0);
        }
    }
    // acc[t][r] = S[q-sub-row = 4u+r][col = 16t+la]

    // ---- retire V-low into fp16 frags; issue V-high (hides under softmax+P) ----
    half8 vfrag[4];
#pragma unroll
    for (int kk = 0; kk < 2; ++kk)
#pragma unroll
        for (int i = 0; i < 8; ++i)
            vfrag[kk][i] = (_Float16)vlo[kk * 8 + i];
    float vhi[16];
#pragma unroll
    for (int kk = 0; kk < 2; ++kk)
#pragma unroll
        for (int i = 0; i < 8; ++i)
            vhi[kk * 8 + i] = Vb[((kk + 2) * 32 + u * 8 + i) * 128 + w * 16 + la];

    // ---------------- row softmax (16 lanes sharing u hold one q-row) ----------------
    float inv[4];
#pragma unroll
    for (int r = 0; r < 4; ++r) {
        float m = acc[0][r];
#pragma unroll
        for (int t = 1; t < 8; ++t) m = fmaxf(m, acc[t][r]);
        m = fmaxf(m, __shfl_xor(m, 1));
        m = fmaxf(m, __shfl_xor(m, 2));
        m = fmaxf(m, __shfl_xor(m, 4));
        m = fmaxf(m, __shfl_xor(m, 8));
        float s = 0.f;
#pragma unroll
        for (int t = 0; t < 8; ++t) {
            const float e = __expf(acc[t][r] - m);
            acc[t][r] = e;
            s += e;
        }
        s += __shfl_xor(s, 1);
        s += __shfl_xor(s, 2);
        s += __shfl_xor(s, 4);
        s += __shfl_xor(s, 8);
        inv[r] = 1.0f / s;
    }

    __syncthreads();                                   // S2: all K reads done

    // ---------------- P -> LDS fp16 (overlay K region), row q swizzled ----------------
#pragma unroll
    for (int t = 0; t < 8; ++t) {
#pragma unroll
        for (int r = 0; r < 4; ++r) {
            const int q   = w * 16 + u * 4 + r;        // global q row
            const int col = t * 16 + la;               // j
            int byte = q * 256 + col * 2;
            byte ^= swz(q & 15);
            *(_Float16*)(smem + byte) = (_Float16)(acc[t][r] * inv[r]);
        }
    }

    // ---- retire V-high ----
#pragma unroll
    for (int kk = 0; kk < 2; ++kk)
#pragma unroll
        for (int i = 0; i < 8; ++i)
            vfrag[2 + kk][i] = (_Float16)vhi[kk * 8 + i];

    __syncthreads();                                   // S3

    // ---------------- O^T = V^T P^T : A = V-frag (m=d), B = P-frag (n=q) ----------------
    // Per q-tile: load B-frags, 4 MFMA over j, store float4 immediately (oacc stays 4 regs).
#pragma unroll
    for (int qt = 0; qt < 8; ++qt) {
        half8 pb[4];
#pragma unroll
        for (int kk = 0; kk < 4; ++kk) {
            int byte = (qt * 16 + la) * 256 + kk * 64 + u * 16;
            byte ^= swz(la);
            pb[kk] = *(const half8*)(smem + byte);
        }
        f32x4 oa = (f32x4){0.f, 0.f, 0.f, 0.f};
#pragma unroll
        for (int kk = 0; kk < 4; ++kk)
            oa = __builtin_amdgcn_mfma_f32_16x16x32_f16(vfrag[kk], pb[kk], oa, 0, 0, 0);
        // lane holds O[q = qt*16+la][d = 16w + 4u + r], r=0..3 -> contiguous float4
        *(float4*)(Ob + (qt * 16 + la) * 128 + w * 16 + u * 4) =
            make_float4(oa[0], oa[1], oa[2], oa[3]);
    }
}

extern "C" void kernel_launch(void* const* d_in, const int* in_sizes, int n_in,
                              void* d_out, int out_size, void* d_ws, size_t ws_size,
                              hipStream_t stream) {
    const float* q = (const float*)d_in[0];
    const float* k = (const float*)d_in[1];
    const float* v = (const float*)d_in[2];
    float* o = (float*)d_out;
    const int nblocks = in_sizes[0] / (128 * 128);   // 4096
    battn_kernel<<<dim3(nblocks), dim3(512), 32768, stream>>>(q, k, v, o);
}

// Round 5
// 214.749 us; speedup vs baseline: 2.5301x; 1.0343x over previous
//
#include <hip/hip_runtime.h>

typedef _Float16 half8  __attribute__((ext_vector_type(8)));
typedef _Float16 half4v __attribute__((ext_vector_type(4)));
typedef float    f32x4  __attribute__((ext_vector_type(4)));

__device__ __forceinline__ int swz(int row) {
    return ((row ^ (row >> 3)) & 15) << 4;   // 256B-row region, 16B granules
}

// One WG = one (b,h,n) 128x128 attention block. 8 waves; wave w owns:
//   QK^T/softmax: q-rows [16w,16w+16)
//   PV:           d-slab  [16w,16w+16)  (V read straight from global, no LDS)
// LDS 64KB: [0,32K)   K fp16 [128][128] swizzled
//           [32K,64K) P fp16 [128 q][128 j] swizzled (separate region -> fewer barriers)
__global__ __launch_bounds__(512, 4) void battn_kernel(
    const float* __restrict__ Q, const float* __restrict__ K,
    const float* __restrict__ V, float* __restrict__ O)
{
    extern __shared__ __align__(16) char smem[];
    const int tid  = threadIdx.x;
    const int lane = tid & 63;
    const int w    = tid >> 6;
    const int la   = lane & 15;
    const int u    = lane >> 4;
    const size_t base = (size_t)blockIdx.x * (128 * 128);

    const float* Qb = Q + base;
    const float* Kb = K + base;
    const float* Vb = V + base;
    float*       Ob = O + base;

    // ---------------- phase 0: K + Q loads, qfrag cvt, K->LDS ----------------
    float4 kreg[8];
#pragma unroll
    for (int it = 0; it < 8; ++it)
        kreg[it] = *(const float4*)(Kb + it * 2048 + tid * 4);

    half8 qfrag[4];
    {
        const float* qrow = Qb + (w * 16 + la) * 128;
#pragma unroll
        for (int kk = 0; kk < 4; ++kk) {
            const float4 a = *(const float4*)(qrow + kk * 32 + u * 8);
            const float4 b = *(const float4*)(qrow + kk * 32 + u * 8 + 4);
            qfrag[kk][0] = (_Float16)a.x; qfrag[kk][1] = (_Float16)a.y;
            qfrag[kk][2] = (_Float16)a.z; qfrag[kk][3] = (_Float16)a.w;
            qfrag[kk][4] = (_Float16)b.x; qfrag[kk][5] = (_Float16)b.y;
            qfrag[kk][6] = (_Float16)b.z; qfrag[kk][7] = (_Float16)b.w;
        }
    }
#pragma unroll
    for (int it = 0; it < 8; ++it) {
        const int idx = it * 2048 + tid * 4;
        const int row = idx >> 7;
        const int col = idx & 127;
        half4v h;
        h[0] = (_Float16)kreg[it].x; h[1] = (_Float16)kreg[it].y;
        h[2] = (_Float16)kreg[it].z; h[3] = (_Float16)kreg[it].w;
        int byte = row * 256 + col * 2;
        byte ^= swz(row);
        *(half4v*)(smem + byte) = h;
    }
    __syncthreads();                                   // S1 (drains K/Q loads only)

    // ---- issue ALL V loads now; pin them here so they overlap QK^T+softmax ----
    // A-frag for PV: lane (la,u) needs V[j = kk*32 + u*8 + i][d = 16w + la]
    float vld[32];
#pragma unroll
    for (int kk = 0; kk < 4; ++kk)
#pragma unroll
        for (int i = 0; i < 8; ++i)
            vld[kk * 8 + i] = Vb[(kk * 32 + u * 8 + i) * 128 + w * 16 + la];
    __builtin_amdgcn_sched_barrier(0);                 // do NOT sink these loads

    // ---------------- S = Q K^T ----------------
    f32x4 acc[8];
#pragma unroll
    for (int t = 0; t < 8; ++t) acc[t] = (f32x4){0.f, 0.f, 0.f, 0.f};
#pragma unroll
    for (int t = 0; t < 8; ++t) {
#pragma unroll
        for (int kk = 0; kk < 4; ++kk) {
            const int row = t * 16 + la;
            int byte = row * 256 + kk * 64 + u * 16;
            byte ^= swz(row);
            const half8 kf = *(const half8*)(smem + byte);
            acc[t] = __builtin_amdgcn_mfma_f32_16x16x32_f16(qfrag[kk], kf, acc[t], 0, 0, 0);
        }
    }
    // acc[t][r] = S[q-sub-row = 4u+r][col = 16t+la]

    // ---------------- row softmax (16 lanes sharing u hold one q-row) ----------------
    float inv[4];
#pragma unroll
    for (int r = 0; r < 4; ++r) {
        float m = acc[0][r];
#pragma unroll
        for (int t = 1; t < 8; ++t) m = fmaxf(m, acc[t][r]);
        m = fmaxf(m, __shfl_xor(m, 1));
        m = fmaxf(m, __shfl_xor(m, 2));
        m = fmaxf(m, __shfl_xor(m, 4));
        m = fmaxf(m, __shfl_xor(m, 8));
        float s = 0.f;
#pragma unroll
        for (int t = 0; t < 8; ++t) {
            const float e = __expf(acc[t][r] - m);
            acc[t][r] = e;
            s += e;
        }
        s += __shfl_xor(s, 1);
        s += __shfl_xor(s, 2);
        s += __shfl_xor(s, 4);
        s += __shfl_xor(s, 8);
        inv[r] = 1.0f / s;
    }

    // ---------------- retire V into fp16 A-frags (waits for V here) ----------------
    half8 vfrag[4];
#pragma unroll
    for (int kk = 0; kk < 4; ++kk)
#pragma unroll
        for (int i = 0; i < 8; ++i)
            vfrag[kk][i] = (_Float16)vld[kk * 8 + i];

    // ---------------- P -> LDS fp16 (own region), row q swizzled ----------------
#pragma unroll
    for (int t = 0; t < 8; ++t) {
#pragma unroll
        for (int r = 0; r < 4; ++r) {
            const int q   = w * 16 + u * 4 + r;        // global q row
            const int col = t * 16 + la;               // j
            int byte = 32768 + q * 256 + col * 2;
            byte ^= swz(q & 15);
            *(_Float16*)(smem + byte) = (_Float16)(acc[t][r] * inv[r]);
        }
    }
    __syncthreads();                                   // S2: P staged

    // ---------------- O^T = V^T P^T : A = V-frag (m=d), B = P-frag (n=q) ----------------
#pragma unroll
    for (int qt = 0; qt < 8; ++qt) {
        half8 pb[4];
#pragma unroll
        for (int kk = 0; kk < 4; ++kk) {
            int byte = 32768 + (qt * 16 + la) * 256 + kk * 64 + u * 16;
            byte ^= swz(la);
            pb[kk] = *(const half8*)(smem + byte);
        }
        f32x4 oa = (f32x4){0.f, 0.f, 0.f, 0.f};
#pragma unroll
        for (int kk = 0; kk < 4; ++kk)
            oa = __builtin_amdgcn_mfma_f32_16x16x32_f16(vfrag[kk], pb[kk], oa, 0, 0, 0);
        // lane holds O[q = qt*16+la][d = 16w + 4u + r], r=0..3 -> contiguous float4
        *(float4*)(Ob + (qt * 16 + la) * 128 + w * 16 + u * 4) =
            make_float4(oa[0], oa[1], oa[2], oa[3]);
    }
}

extern "C" void kernel_launch(void* const* d_in, const int* in_sizes, int n_in,
                              void* d_out, int out_size, void* d_ws, size_t ws_size,
                              hipStream_t stream) {
    const float* q = (const float*)d_in[0];
    const float* k = (const float*)d_in[1];
    const float* v = (const float*)d_in[2];
    float* o = (float*)d_out;
    const int nblocks = in_sizes[0] / (128 * 128);   // 4096
    battn_kernel<<<dim3(nblocks), dim3(512), 65536, stream>>>(q, k, v, o);
}

// Round 6
// 211.747 us; speedup vs baseline: 2.5660x; 1.0142x over previous
//
#include <hip/hip_runtime.h>

typedef _Float16 half8  __attribute__((ext_vector_type(8)));
typedef _Float16 half4v __attribute__((ext_vector_type(4)));
typedef float    f32x4  __attribute__((ext_vector_type(4)));

__device__ __forceinline__ int swz(int row) {
    return ((row ^ (row >> 3)) & 15) << 4;   // 256B-row region, 16B granules
}

// One WG = one (b,h,n) 128x128 attention block. 8 waves; wave w owns:
//   QK^T/softmax: q-rows [16w,16w+16)
//   PV:           d-slab  [16w,16w+16)  (V read straight from global, once per WG)
// LDS 32KB total: K fp16 [128][128] swizzled; P fp16 overlays it after the K-done
// barrier. VGPR pinned <=64 by __launch_bounds__(512,8): 4 WGs/CU = 32 waves/CU,
// latency hidden by TLP instead of register prefetch (which the compiler defeats).
__global__ __launch_bounds__(512, 8) void battn_kernel(
    const float* __restrict__ Q, const float* __restrict__ K,
    const float* __restrict__ V, float* __restrict__ O)
{
    __shared__ __align__(16) char smem[32768];
    const int tid  = threadIdx.x;
    const int lane = tid & 63;
    const int w    = tid >> 6;
    const int la   = lane & 15;
    const int u    = lane >> 4;
    const size_t base = (size_t)blockIdx.x * (128 * 128);

    const float* Qb = Q + base;
    const float* Kb = K + base;
    const float* Vb = V + base;
    float*       Ob = O + base;

    // ---------------- phase 0: K + Q loads, qfrag cvt, K->LDS ----------------
    float4 kreg[8];
#pragma unroll
    for (int it = 0; it < 8; ++it)
        kreg[it] = *(const float4*)(Kb + it * 2048 + tid * 4);

    half8 qfrag[4];
    {
        const float* qrow = Qb + (w * 16 + la) * 128;
#pragma unroll
        for (int kk = 0; kk < 4; ++kk) {
            const float4 a = *(const float4*)(qrow + kk * 32 + u * 8);
            const float4 b = *(const float4*)(qrow + kk * 32 + u * 8 + 4);
            qfrag[kk][0] = (_Float16)a.x; qfrag[kk][1] = (_Float16)a.y;
            qfrag[kk][2] = (_Float16)a.z; qfrag[kk][3] = (_Float16)a.w;
            qfrag[kk][4] = (_Float16)b.x; qfrag[kk][5] = (_Float16)b.y;
            qfrag[kk][6] = (_Float16)b.z; qfrag[kk][7] = (_Float16)b.w;
        }
    }
#pragma unroll
    for (int it = 0; it < 8; ++it) {
        const int idx = it * 2048 + tid * 4;
        const int row = idx >> 7;
        const int col = idx & 127;
        half4v h;
        h[0] = (_Float16)kreg[it].x; h[1] = (_Float16)kreg[it].y;
        h[2] = (_Float16)kreg[it].z; h[3] = (_Float16)kreg[it].w;
        int byte = row * 256 + col * 2;
        byte ^= swz(row);
        *(half4v*)(smem + byte) = h;
    }
    __syncthreads();                                   // S1: K staged

    // ---------------- S = Q K^T ----------------
    f32x4 acc[8];
#pragma unroll
    for (int t = 0; t < 8; ++t) acc[t] = (f32x4){0.f, 0.f, 0.f, 0.f};
#pragma unroll
    for (int t = 0; t < 8; ++t) {
#pragma unroll
        for (int kk = 0; kk < 4; ++kk) {
            const int row = t * 16 + la;
            int byte = row * 256 + kk * 64 + u * 16;
            byte ^= swz(row);
            const half8 kf = *(const half8*)(smem + byte);
            acc[t] = __builtin_amdgcn_mfma_f32_16x16x32_f16(qfrag[kk], kf, acc[t], 0, 0, 0);
        }
    }
    // acc[t][r] = S[q-sub-row = 4u+r][col = 16t+la]

    // ---------------- row softmax (16 lanes sharing u hold one q-row) ----------------
    float inv[4];
#pragma unroll
    for (int r = 0; r < 4; ++r) {
        float m = acc[0][r];
#pragma unroll
        for (int t = 1; t < 8; ++t) m = fmaxf(m, acc[t][r]);
        m = fmaxf(m, __shfl_xor(m, 1));
        m = fmaxf(m, __shfl_xor(m, 2));
        m = fmaxf(m, __shfl_xor(m, 4));
        m = fmaxf(m, __shfl_xor(m, 8));
        float s = 0.f;
#pragma unroll
        for (int t = 0; t < 8; ++t) {
            const float e = __expf(acc[t][r] - m);
            acc[t][r] = e;
            s += e;
        }
        s += __shfl_xor(s, 1);
        s += __shfl_xor(s, 2);
        s += __shfl_xor(s, 4);
        s += __shfl_xor(s, 8);
        inv[r] = 1.0f / s;
    }

    __syncthreads();                                   // S2: all K reads done

    // ---------------- P -> LDS fp16 (overlay K region), acc dies here ----------------
#pragma unroll
    for (int t = 0; t < 8; ++t) {
#pragma unroll
        for (int r = 0; r < 4; ++r) {
            const int q   = w * 16 + u * 4 + r;        // global q row
            const int col = t * 16 + la;               // j
            int byte = q * 256 + col * 2;
            byte ^= swz(q & 15);
            *(_Float16*)(smem + byte) = (_Float16)(acc[t][r] * inv[r]);
        }
    }

    // ---------------- issue V loads (acc dead -> pressure OK); overlap S3 wait ----
    // A-frag for PV: lane (la,u) needs V[j = kk*32 + u*8 + i][d = 16w + la]
    float vld[32];
#pragma unroll
    for (int kk = 0; kk < 4; ++kk)
#pragma unroll
        for (int i = 0; i < 8; ++i)
            vld[kk * 8 + i] = Vb[(kk * 32 + u * 8 + i) * 128 + w * 16 + la];

    __syncthreads();                                   // S3: P staged (V still in flight)

    half8 vfrag[4];
#pragma unroll
    for (int kk = 0; kk < 4; ++kk)
#pragma unroll
        for (int i = 0; i < 8; ++i)
            vfrag[kk][i] = (_Float16)vld[kk * 8 + i];

    // ---------------- O^T = V^T P^T : A = V-frag (m=d), B = P-frag (n=q) ----------------
#pragma unroll
    for (int qt = 0; qt < 8; ++qt) {
        half8 pb[4];
#pragma unroll
        for (int kk = 0; kk < 4; ++kk) {
            int byte = (qt * 16 + la) * 256 + kk * 64 + u * 16;
            byte ^= swz(la);
            pb[kk] = *(const half8*)(smem + byte);
        }
        f32x4 oa = (f32x4){0.f, 0.f, 0.f, 0.f};
#pragma unroll
        for (int kk = 0; kk < 4; ++kk)
            oa = __builtin_amdgcn_mfma_f32_16x16x32_f16(vfrag[kk], pb[kk], oa, 0, 0, 0);
        // lane holds O[q = qt*16+la][d = 16w + 4u + r], r=0..3 -> contiguous float4
        *(float4*)(Ob + (qt * 16 + la) * 128 + w * 16 + u * 4) =
            make_float4(oa[0], oa[1], oa[2], oa[3]);
    }
}

extern "C" void kernel_launch(void* const* d_in, const int* in_sizes, int n_in,
                              void* d_out, int out_size, void* d_ws, size_t ws_size,
                              hipStream_t stream) {
    const float* q = (const float*)d_in[0];
    const float* k = (const float*)d_in[1];
    const float* v = (const float*)d_in[2];
    float* o = (float*)d_out;
    const int nblocks = in_sizes[0] / (128 * 128);   // 4096
    battn_kernel<<<dim3(nblocks), dim3(512), 0, stream>>>(q, k, v, o);
}